// Round 2
// baseline (286.325 us; speedup 1.0000x reference)
//
#include <hip/hip_runtime.h>
#include <stdint.h>

#define T_TOK  2048
#define HID    1024
#define INTERN 2048
#define NEXP   8

typedef __attribute__((ext_vector_type(8))) short          bf16x8;
typedef __attribute__((ext_vector_type(4))) float          f32x4;
typedef __attribute__((ext_vector_type(8))) unsigned short u16x8;
typedef __attribute__((ext_vector_type(4))) unsigned short u16x4;

__device__ __forceinline__ unsigned short f32_to_bf16(float f) {
  unsigned int u = __float_as_uint(f);
  unsigned int r = (u + 0x7FFFu + ((u >> 16) & 1u)) >> 16;
  return (unsigned short)r;
}

__device__ __forceinline__ void gload_lds16(const void* g, void* l) {
  __builtin_amdgcn_global_load_lds(
      (const __attribute__((address_space(1))) unsigned int*)g,
      (__attribute__((address_space(3))) unsigned int*)l, 16, 0, 0);
}

// ---------------- routing: build per-expert compact lists ----------------
__global__ void route_kernel(const int* __restrict__ tki,   // int32 per harness contract
                             const float* __restrict__ tkw,
                             int* __restrict__ counts,
                             int* __restrict__ offsets,
                             int* __restrict__ tok_list,
                             float* __restrict__ w_list,
                             int* __restrict__ pos_map,
                             float* __restrict__ wgt_map) {
  __shared__ int scnt[NEXP];
  __shared__ int soff[NEXP];
  int tid = threadIdx.x;
  if (tid < NEXP) scnt[tid] = 0;
  __syncthreads();
  for (int t = tid; t < T_TOK; t += 256) {
    int e0 = tki[2 * t] & 7;
    int e1 = tki[2 * t + 1] & 7;
    float w0 = tkw[2 * t];
    float w1 = tkw[2 * t + 1];
    if (e0 == e1) {
      int p = atomicAdd(&scnt[e0], 1);
      tok_list[e0 * T_TOK + p] = t;
      w_list [e0 * T_TOK + p] = w0 + w1;
      pos_map[2 * t]     = (p << 3) | e0;
      wgt_map[2 * t]     = w0 + w1;
      pos_map[2 * t + 1] = -1;
      wgt_map[2 * t + 1] = 0.0f;
    } else {
      int p = atomicAdd(&scnt[e0], 1);
      tok_list[e0 * T_TOK + p] = t;
      w_list [e0 * T_TOK + p] = w0;
      pos_map[2 * t]     = (p << 3) | e0;
      wgt_map[2 * t]     = w0;
      int q = atomicAdd(&scnt[e1], 1);
      tok_list[e1 * T_TOK + q] = t;
      w_list [e1 * T_TOK + q] = w1;
      pos_map[2 * t + 1] = (q << 3) | e1;
      wgt_map[2 * t + 1] = w1;
    }
  }
  __syncthreads();
  if (tid == 0) {
    int acc = 0;
    for (int e = 0; e < NEXP; ++e) {
      counts[e]  = scnt[e];
      offsets[e] = acc;
      soff[e]    = acc;
      acc += scnt[e];
    }
  }
  __syncthreads();
  for (int i = tid; i < 2 * T_TOK; i += 256) {
    int v = pos_map[i];
    if (v >= 0) pos_map[i] = soff[v & 7] + (v >> 3);
  }
}

// ---------------- hidden_states f32 -> bf16 ----------------
__global__ void cvt_x_kernel(const float* __restrict__ x, unsigned short* __restrict__ xb) {
  int i = blockIdx.x * 256 + threadIdx.x;
  float4 v = ((const float4*)x)[i];
  u16x4 o;
  o[0] = f32_to_bf16(v.x); o[1] = f32_to_bf16(v.y);
  o[2] = f32_to_bf16(v.z); o[3] = f32_to_bf16(v.w);
  *((u16x4*)(xb + 4 * (size_t)i)) = o;
}

// ---------------- zero-fill out (capture-safe) ----------------
__global__ void zero_out_kernel(float* __restrict__ out) {
  int i = blockIdx.x * 256 + threadIdx.x;
  ((float4*)out)[i] = make_float4(0.f, 0.f, 0.f, 0.f);
}

// ---------------- GEMM1: h = gelu_tanh(X Wg^T) * (X Wu^T), per expert ----------------
// block: 128 rows x 64 h-cols (gate tile + up tile fused). 4 waves, wave tile 64x32.
__global__ __launch_bounds__(256, 2)
void gemm1_kernel(const unsigned short* __restrict__ xb,
                  const float* __restrict__ gup,
                  const int* __restrict__ counts,
                  const int* __restrict__ offsets,
                  const int* __restrict__ tok_list,
                  unsigned short* __restrict__ hbuf) {
  int e  = blockIdx.z;
  int Ne = counts[e];
  int m0 = blockIdx.y * 128;
  if (m0 >= Ne) return;
  int n0  = blockIdx.x * 64;
  int off = offsets[e];

  __shared__ __align__(16) unsigned short As[4][128][8];  // [kg][row][8] K-major bf16
  __shared__ __align__(16) unsigned short Gs[4][64][8];
  __shared__ __align__(16) unsigned short Us[4][64][8];

  int tid  = threadIdx.x;
  int lane = tid & 63;
  int wave = tid >> 6;
  int wm = wave >> 1;
  int wn = wave & 1;

  // A staging: one row per thread, two kg-slots
  int arow = tid & 127;
  int akg  = tid >> 7;  // 0/1 (second issue +2)
  int rg   = m0 + arow;
  int tok  = (rg < Ne) ? tok_list[e * T_TOK + rg] : 0;
  const unsigned short* asrc = xb + (size_t)tok * HID;

  // B staging: row = tid>>2 (0..63), kg = tid&3 -> 8 consecutive f32
  int brow = tid >> 2;
  int bkg  = tid & 3;
  const float* gsrc = gup + (size_t)e * (2 * INTERN) * HID + (size_t)(n0 + brow) * HID + bkg * 8;
  const float* usrc = gsrc + (size_t)INTERN * HID;

  f32x4 accg[4][2], accu[4][2];
#pragma unroll
  for (int m = 0; m < 4; ++m)
#pragma unroll
    for (int n = 0; n < 2; ++n) {
      accg[m][n] = (f32x4){0.f, 0.f, 0.f, 0.f};
      accu[m][n] = (f32x4){0.f, 0.f, 0.f, 0.f};
    }

  char* AsB = (char*)&As[0][0][0];

  for (int k0 = 0; k0 < HID; k0 += 32) {
    gload_lds16(asrc + k0 + akg * 8,       AsB + (size_t)tid * 16);
    gload_lds16(asrc + k0 + (akg + 2) * 8, AsB + (size_t)(256 + tid) * 16);
    float4 g0 = *(const float4*)(gsrc + k0);
    float4 g1 = *(const float4*)(gsrc + k0 + 4);
    float4 u0 = *(const float4*)(usrc + k0);
    float4 u1 = *(const float4*)(usrc + k0 + 4);
    u16x8 gw, uw;
    gw[0] = f32_to_bf16(g0.x); gw[1] = f32_to_bf16(g0.y);
    gw[2] = f32_to_bf16(g0.z); gw[3] = f32_to_bf16(g0.w);
    gw[4] = f32_to_bf16(g1.x); gw[5] = f32_to_bf16(g1.y);
    gw[6] = f32_to_bf16(g1.z); gw[7] = f32_to_bf16(g1.w);
    uw[0] = f32_to_bf16(u0.x); uw[1] = f32_to_bf16(u0.y);
    uw[2] = f32_to_bf16(u0.z); uw[3] = f32_to_bf16(u0.w);
    uw[4] = f32_to_bf16(u1.x); uw[5] = f32_to_bf16(u1.y);
    uw[6] = f32_to_bf16(u1.z); uw[7] = f32_to_bf16(u1.w);
    *((u16x8*)&Gs[bkg][brow][0]) = gw;
    *((u16x8*)&Us[bkg][brow][0]) = uw;
    __syncthreads();

    int kg = lane >> 4;
    int rl = lane & 15;
    bf16x8 af[4], gf[2], uf[2];
#pragma unroll
    for (int m = 0; m < 4; ++m)
      af[m] = *((const bf16x8*)&As[kg][wm * 64 + m * 16 + rl][0]);
#pragma unroll
    for (int n = 0; n < 2; ++n) {
      gf[n] = *((const bf16x8*)&Gs[kg][wn * 32 + n * 16 + rl][0]);
      uf[n] = *((const bf16x8*)&Us[kg][wn * 32 + n * 16 + rl][0]);
    }
#pragma unroll
    for (int m = 0; m < 4; ++m)
#pragma unroll
      for (int n = 0; n < 2; ++n) {
        accg[m][n] = __builtin_amdgcn_mfma_f32_16x16x32_bf16(af[m], gf[n], accg[m][n], 0, 0, 0);
        accu[m][n] = __builtin_amdgcn_mfma_f32_16x16x32_bf16(af[m], uf[n], accu[m][n], 0, 0, 0);
      }
    __syncthreads();
  }

  int rl = lane & 15;
  int rq = lane >> 4;
#pragma unroll
  for (int m = 0; m < 4; ++m) {
#pragma unroll
    for (int n = 0; n < 2; ++n) {
      int col = n0 + wn * 32 + n * 16 + rl;
#pragma unroll
      for (int j = 0; j < 4; ++j) {
        int r = m0 + wm * 64 + m * 16 + rq * 4 + j;
        if (r < Ne) {
          float gv = accg[m][n][j];
          float uv = accu[m][n][j];
          float t  = gv + 0.044715f * gv * gv * gv;
          float a  = gv / (1.0f + __expf(-1.5957691216f * t));  // x*sigmoid(2c(x+0.044715x^3)) == gelu_tanh
          hbuf[(size_t)(off + r) * INTERN + col] = f32_to_bf16(a * uv);
        }
      }
    }
  }
}

// ---------------- GEMM2: y = h Wd^T (compact rows) ----------------
__global__ __launch_bounds__(256, 2)
void gemm2_kernel(const unsigned short* __restrict__ hbuf,
                  const float* __restrict__ down,
                  const int* __restrict__ counts,
                  const int* __restrict__ offsets,
                  const int* __restrict__ tok_list,
                  const float* __restrict__ w_list,
                  float* __restrict__ ybuf,
                  float* __restrict__ out,
                  int use_y) {
  int e  = blockIdx.z;
  int Ne = counts[e];
  int m0 = blockIdx.y * 128;
  if (m0 >= Ne) return;
  int n0  = blockIdx.x * 64;
  int off = offsets[e];

  __shared__ __align__(16) unsigned short As[4][128][8];
  __shared__ __align__(16) unsigned short Bs[4][64][8];

  int tid  = threadIdx.x;
  int lane = tid & 63;
  int wave = tid >> 6;
  int wm = wave >> 1;
  int wn = wave & 1;

  int arow = tid & 127;
  int akg  = tid >> 7;
  const unsigned short* asrc = hbuf + (size_t)(off + m0 + arow) * INTERN;

  int brow = tid >> 2;
  int bkg  = tid & 3;
  const float* bsrc = down + (size_t)e * HID * INTERN + (size_t)(n0 + brow) * INTERN + bkg * 8;

  f32x4 acc[4][2];
#pragma unroll
  for (int m = 0; m < 4; ++m)
#pragma unroll
    for (int n = 0; n < 2; ++n) acc[m][n] = (f32x4){0.f, 0.f, 0.f, 0.f};

  char* AsB = (char*)&As[0][0][0];

  for (int k0 = 0; k0 < INTERN; k0 += 32) {
    gload_lds16(asrc + k0 + akg * 8,       AsB + (size_t)tid * 16);
    gload_lds16(asrc + k0 + (akg + 2) * 8, AsB + (size_t)(256 + tid) * 16);
    float4 b0 = *(const float4*)(bsrc + k0);
    float4 b1 = *(const float4*)(bsrc + k0 + 4);
    u16x8 bw;
    bw[0] = f32_to_bf16(b0.x); bw[1] = f32_to_bf16(b0.y);
    bw[2] = f32_to_bf16(b0.z); bw[3] = f32_to_bf16(b0.w);
    bw[4] = f32_to_bf16(b1.x); bw[5] = f32_to_bf16(b1.y);
    bw[6] = f32_to_bf16(b1.z); bw[7] = f32_to_bf16(b1.w);
    *((u16x8*)&Bs[bkg][brow][0]) = bw;
    __syncthreads();

    int kg = lane >> 4;
    int rl = lane & 15;
    bf16x8 af[4], bfv[2];
#pragma unroll
    for (int m = 0; m < 4; ++m)
      af[m] = *((const bf16x8*)&As[kg][wm * 64 + m * 16 + rl][0]);
#pragma unroll
    for (int n = 0; n < 2; ++n)
      bfv[n] = *((const bf16x8*)&Bs[kg][wn * 32 + n * 16 + rl][0]);
#pragma unroll
    for (int m = 0; m < 4; ++m)
#pragma unroll
      for (int n = 0; n < 2; ++n)
        acc[m][n] = __builtin_amdgcn_mfma_f32_16x16x32_bf16(af[m], bfv[n], acc[m][n], 0, 0, 0);
    __syncthreads();
  }

  int rl = lane & 15;
  int rq = lane >> 4;
#pragma unroll
  for (int m = 0; m < 4; ++m) {
#pragma unroll
    for (int n = 0; n < 2; ++n) {
      int col = n0 + wn * 32 + n * 16 + rl;
#pragma unroll
      for (int j = 0; j < 4; ++j) {
        int r = m0 + wm * 64 + m * 16 + rq * 4 + j;
        if (r < Ne) {
          float v = acc[m][n][j];
          if (use_y) {
            ybuf[(size_t)(off + r) * HID + col] = v;
          } else {
            int   tk = tok_list[e * T_TOK + r];
            float w  = w_list [e * T_TOK + r];
            atomicAdd(out + (size_t)tk * HID + col, w * v);
          }
        }
      }
    }
  }
}

// ---------------- final combine: out[t] = sum_k w[t,k] * y[pos[t,k]] ----------------
__global__ void combine_kernel(const int* __restrict__ pos_map,
                               const float* __restrict__ wgt_map,
                               const float* __restrict__ ybuf,
                               float* __restrict__ out) {
  int i  = blockIdx.x * 256 + threadIdx.x;
  int t  = i >> 8;      // 256 float4 per token row
  int c4 = i & 255;
  int p0 = pos_map[2 * t];
  int p1 = pos_map[2 * t + 1];
  float w0 = wgt_map[2 * t];
  float w1 = wgt_map[2 * t + 1];
  float4 a = make_float4(0.f, 0.f, 0.f, 0.f);
  if (p0 >= 0) {
    float4 v = ((const float4*)(ybuf + (size_t)p0 * HID))[c4];
    a.x += w0 * v.x; a.y += w0 * v.y; a.z += w0 * v.z; a.w += w0 * v.w;
  }
  if (p1 >= 0) {
    float4 v = ((const float4*)(ybuf + (size_t)p1 * HID))[c4];
    a.x += w1 * v.x; a.y += w1 * v.y; a.z += w1 * v.z; a.w += w1 * v.w;
  }
  ((float4*)(out + (size_t)t * HID))[c4] = a;
}

// ---------------- launch ----------------
extern "C" void kernel_launch(void* const* d_in, const int* in_sizes, int n_in,
                              void* d_out, int out_size, void* d_ws, size_t ws_size,
                              hipStream_t stream) {
  (void)in_sizes; (void)n_in; (void)out_size;
  const float* hidden = (const float*)d_in[0];
  const int*   tki    = (const int*)d_in[1];   // int32 per harness contract
  const float* tkw    = (const float*)d_in[2];
  const float* gup    = (const float*)d_in[3];
  const float* down   = (const float*)d_in[4];
  float* out = (float*)d_out;
  char*  ws  = (char*)d_ws;

  // ws layout (bytes)
  int*   counts   = (int*)  (ws + 0);         // 8 ints
  int*   offsets  = (int*)  (ws + 64);        // 8 ints
  int*   tok_list = (int*)  (ws + 256);       // 8*2048 -> end 65792
  int*   pos_map  = (int*)  (ws + 65792);     // 4096   -> end 82176
  float* wgt_map  = (float*)(ws + 82176);     // 4096   -> end 98560
  float* w_list   = (float*)(ws + 98560);     // 8*2048 -> end 164096
  unsigned short* xb   = (unsigned short*)(ws + 164096);   // 2048*1024 bf16 -> end 4358400
  unsigned short* hbuf = (unsigned short*)(ws + 4358400);  // 4224*2048 bf16 -> end 21659904
  float* ybuf = (float*)(ws + 21659904);                   // 4224*1024 f32  -> end 38961408

  if (ws_size < 21659904ull) return;  // cannot run at all
  int use_y = (ws_size >= 38961408ull) ? 1 : 0;

  hipLaunchKernelGGL(route_kernel, dim3(1), dim3(256), 0, stream,
                     tki, tkw, counts, offsets, tok_list, w_list, pos_map, wgt_map);
  hipLaunchKernelGGL(cvt_x_kernel, dim3((T_TOK * HID / 4) / 256), dim3(256), 0, stream,
                     hidden, xb);
  hipLaunchKernelGGL(gemm1_kernel, dim3(INTERN / 64, T_TOK / 128, NEXP), dim3(256), 0, stream,
                     xb, gup, counts, offsets, tok_list, hbuf);
  if (!use_y)
    hipLaunchKernelGGL(zero_out_kernel, dim3((T_TOK * HID / 4) / 256), dim3(256), 0, stream, out);
  hipLaunchKernelGGL(gemm2_kernel, dim3(HID / 64, T_TOK / 128, NEXP), dim3(256), 0, stream,
                     hbuf, down, counts, offsets, tok_list, w_list, ybuf, out, use_y);
  if (use_y)
    hipLaunchKernelGGL(combine_kernel, dim3(T_TOK * HID / 4 / 256), dim3(256), 0, stream,
                       pos_map, wgt_map, ybuf, out);
}

// Round 3
// 193.666 us; speedup vs baseline: 1.4784x; 1.4784x over previous
//
#include <hip/hip_runtime.h>
#include <stdint.h>

#define T_TOK  2048
#define HID    1024
#define INTERN 2048
#define NEXP   8
#define MAXPOS 5248   // max 128-aligned routed rows: 4096 + 8*127 -> pad to 5248

typedef __attribute__((ext_vector_type(8))) short          bf16x8;
typedef __attribute__((ext_vector_type(4))) float          f32x4;
typedef __attribute__((ext_vector_type(8))) unsigned short u16x8;
typedef __attribute__((ext_vector_type(4))) unsigned short u16x4;

__device__ __forceinline__ unsigned short f32_to_bf16(float f) {
  unsigned int u = __float_as_uint(f);
  unsigned int r = (u + 0x7FFFu + ((u >> 16) & 1u)) >> 16;
  return (unsigned short)r;
}

__device__ __forceinline__ float bf16_to_f32(unsigned short h) {
  unsigned int u = ((unsigned int)h) << 16;
  return __uint_as_float(u);
}

__device__ __forceinline__ void gload_lds16(const void* g, void* l) {
  __builtin_amdgcn_global_load_lds(
      (const __attribute__((address_space(1))) unsigned int*)g,
      (__attribute__((address_space(3))) unsigned int*)l, 16, 0, 0);
}

// ---------------- routing: build per-expert compact lists (128-aligned offsets) ----------------
__global__ void route_kernel(const int* __restrict__ tki,   // int32 per harness contract
                             const float* __restrict__ tkw,
                             int* __restrict__ counts,
                             int* __restrict__ offsets,     // 128-aligned base per expert
                             int* __restrict__ tok_list,
                             float* __restrict__ w_list,
                             int* __restrict__ pos_map,     // aligned global positions
                             float* __restrict__ wgt_map) {
  __shared__ int scnt[NEXP];
  __shared__ int soff[NEXP];
  int tid = threadIdx.x;
  if (tid < NEXP) scnt[tid] = 0;
  __syncthreads();
  for (int t = tid; t < T_TOK; t += 256) {
    int e0 = tki[2 * t] & 7;
    int e1 = tki[2 * t + 1] & 7;
    float w0 = tkw[2 * t];
    float w1 = tkw[2 * t + 1];
    if (e0 == e1) {
      int p = atomicAdd(&scnt[e0], 1);
      tok_list[e0 * T_TOK + p] = t;
      w_list [e0 * T_TOK + p] = w0 + w1;
      pos_map[2 * t]     = (p << 3) | e0;
      wgt_map[2 * t]     = w0 + w1;
      pos_map[2 * t + 1] = -1;
      wgt_map[2 * t + 1] = 0.0f;
    } else {
      int p = atomicAdd(&scnt[e0], 1);
      tok_list[e0 * T_TOK + p] = t;
      w_list [e0 * T_TOK + p] = w0;
      pos_map[2 * t]     = (p << 3) | e0;
      wgt_map[2 * t]     = w0;
      int q = atomicAdd(&scnt[e1], 1);
      tok_list[e1 * T_TOK + q] = t;
      w_list [e1 * T_TOK + q] = w1;
      pos_map[2 * t + 1] = (q << 3) | e1;
      wgt_map[2 * t + 1] = w1;
    }
  }
  __syncthreads();
  if (tid == 0) {
    int acc = 0;
    for (int e = 0; e < NEXP; ++e) {
      counts[e]  = scnt[e];
      offsets[e] = acc;
      soff[e]    = acc;
      acc += ((scnt[e] + 127) >> 7) << 7;   // 128-aligned segments
    }
  }
  __syncthreads();
  for (int i = tid; i < 2 * T_TOK; i += 256) {
    int v = pos_map[i];
    if (v >= 0) pos_map[i] = soff[v & 7] + (v >> 3);
  }
}

// ---------------- hidden_states f32 -> bf16 (row-major, 4MB; L2-resident) ----------------
__global__ void cvt_x_kernel(const float* __restrict__ x, unsigned short* __restrict__ xb) {
  int i = blockIdx.x * 256 + threadIdx.x;
  float4 v = ((const float4*)x)[i];
  u16x4 o;
  o[0] = f32_to_bf16(v.x); o[1] = f32_to_bf16(v.y);
  o[2] = f32_to_bf16(v.z); o[3] = f32_to_bf16(v.w);
  *((u16x4*)(xb + 4 * (size_t)i)) = o;
}

// ---------------- GEMM1: h = gelu_tanh(X Wg^T) * (X Wu^T), per expert ----------------
// A gathered from xb (rows via tok_list). Output h written to BLOCKED layout:
// hbuf[(p>>7)*(INTERN*128) + (col>>3)*1024 + (p&127)*8 + (col&7)],  p = aligned pos.
__global__ __launch_bounds__(256, 2)
void gemm1_kernel(const unsigned short* __restrict__ xb,
                  const float* __restrict__ gup,
                  const int* __restrict__ counts,
                  const int* __restrict__ offsets,
                  const int* __restrict__ tok_list,
                  unsigned short* __restrict__ hbuf) {
  int e  = blockIdx.z;
  int Ne = counts[e];
  int m0 = blockIdx.y * 128;
  if (m0 >= Ne) return;
  int n0  = blockIdx.x * 64;
  int off = offsets[e];   // 128-aligned

  __shared__ __align__(16) unsigned short As[4][128][8];  // [kg][row][8] K-major bf16
  __shared__ __align__(16) unsigned short Gs[4][64][8];
  __shared__ __align__(16) unsigned short Us[4][64][8];

  int tid  = threadIdx.x;
  int lane = tid & 63;
  int wave = tid >> 6;
  int wm = wave >> 1;
  int wn = wave & 1;

  // A staging: one row per thread, two kg-slots
  int arow = tid & 127;
  int akg  = tid >> 7;  // 0/1 (second issue +2)
  int rg   = m0 + arow;
  int tok  = (rg < Ne) ? tok_list[e * T_TOK + rg] : 0;
  const unsigned short* asrc = xb + (size_t)tok * HID;

  // B staging: row = tid>>2 (0..63), kg = tid&3 -> 8 consecutive f32
  int brow = tid >> 2;
  int bkg  = tid & 3;
  const float* gsrc = gup + (size_t)e * (2 * INTERN) * HID + (size_t)(n0 + brow) * HID + bkg * 8;
  const float* usrc = gsrc + (size_t)INTERN * HID;

  f32x4 accg[4][2], accu[4][2];
#pragma unroll
  for (int m = 0; m < 4; ++m)
#pragma unroll
    for (int n = 0; n < 2; ++n) {
      accg[m][n] = (f32x4){0.f, 0.f, 0.f, 0.f};
      accu[m][n] = (f32x4){0.f, 0.f, 0.f, 0.f};
    }

  char* AsB = (char*)&As[0][0][0];
  int brow_w = brow ^ bkg;   // XOR-swizzle rows on write to kill ds_write bank conflict

  for (int k0 = 0; k0 < HID; k0 += 32) {
    gload_lds16(asrc + k0 + akg * 8,       AsB + (size_t)tid * 16);
    gload_lds16(asrc + k0 + (akg + 2) * 8, AsB + (size_t)(256 + tid) * 16);
    float4 g0 = *(const float4*)(gsrc + k0);
    float4 g1 = *(const float4*)(gsrc + k0 + 4);
    float4 u0 = *(const float4*)(usrc + k0);
    float4 u1 = *(const float4*)(usrc + k0 + 4);
    u16x8 gw, uw;
    gw[0] = f32_to_bf16(g0.x); gw[1] = f32_to_bf16(g0.y);
    gw[2] = f32_to_bf16(g0.z); gw[3] = f32_to_bf16(g0.w);
    gw[4] = f32_to_bf16(g1.x); gw[5] = f32_to_bf16(g1.y);
    gw[6] = f32_to_bf16(g1.z); gw[7] = f32_to_bf16(g1.w);
    uw[0] = f32_to_bf16(u0.x); uw[1] = f32_to_bf16(u0.y);
    uw[2] = f32_to_bf16(u0.z); uw[3] = f32_to_bf16(u0.w);
    uw[4] = f32_to_bf16(u1.x); uw[5] = f32_to_bf16(u1.y);
    uw[6] = f32_to_bf16(u1.z); uw[7] = f32_to_bf16(u1.w);
    *((u16x8*)&Gs[bkg][brow_w][0]) = gw;
    *((u16x8*)&Us[bkg][brow_w][0]) = uw;
    __syncthreads();

    int kg = lane >> 4;
    int rl = lane & 15;
    bf16x8 af[4], gf[2], uf[2];
#pragma unroll
    for (int m = 0; m < 4; ++m)
      af[m] = *((const bf16x8*)&As[kg][wm * 64 + m * 16 + rl][0]);
#pragma unroll
    for (int n = 0; n < 2; ++n) {
      gf[n] = *((const bf16x8*)&Gs[kg][(wn * 32 + n * 16 + rl) ^ kg][0]);
      uf[n] = *((const bf16x8*)&Us[kg][(wn * 32 + n * 16 + rl) ^ kg][0]);
    }
#pragma unroll
    for (int m = 0; m < 4; ++m)
#pragma unroll
      for (int n = 0; n < 2; ++n) {
        accg[m][n] = __builtin_amdgcn_mfma_f32_16x16x32_bf16(af[m], gf[n], accg[m][n], 0, 0, 0);
        accu[m][n] = __builtin_amdgcn_mfma_f32_16x16x32_bf16(af[m], uf[n], accu[m][n], 0, 0, 0);
      }
    __syncthreads();
  }

  int rl = lane & 15;
  int rq = lane >> 4;
  size_t hb_base = (size_t)((off + m0) >> 7) * (INTERN * 128);
#pragma unroll
  for (int m = 0; m < 4; ++m) {
#pragma unroll
    for (int n = 0; n < 2; ++n) {
      int col = n0 + wn * 32 + n * 16 + rl;
      size_t cbase = hb_base + (size_t)(col >> 3) * 1024 + (col & 7);
#pragma unroll
      for (int j = 0; j < 4; ++j) {
        int lr = wm * 64 + m * 16 + rq * 4 + j;   // local row 0..127
        if (m0 + lr < Ne) {
          float gv = accg[m][n][j];
          float uv = accu[m][n][j];
          float t  = gv + 0.044715f * gv * gv * gv;
          float a  = gv / (1.0f + __expf(-1.5957691216f * t));  // == gelu_pytorch_tanh
          hbuf[cbase + (size_t)lr * 8] = f32_to_bf16(a * uv);
        }
      }
    }
  }
}

// ---------------- GEMM2: y = h Wd^T (blocked-A, linear DMA staging) ----------------
__global__ __launch_bounds__(256, 2)
void gemm2_kernel(const unsigned short* __restrict__ hbuf,
                  const float* __restrict__ down,
                  const int* __restrict__ counts,
                  const int* __restrict__ offsets,
                  unsigned short* __restrict__ ybuf) {
  int e  = blockIdx.z;
  int Ne = counts[e];
  int m0 = blockIdx.y * 128;
  if (m0 >= Ne) return;
  int n0  = blockIdx.x * 64;
  int off = offsets[e];   // 128-aligned

  __shared__ __align__(16) unsigned short As[4][128][8];
  __shared__ __align__(16) unsigned short Bs[4][64][8];

  int tid  = threadIdx.x;
  int lane = tid & 63;
  int wave = tid >> 6;
  int wm = wave >> 1;
  int wn = wave & 1;

  // A staging: hbuf blocked layout -> fully linear DMA (src and LDS both tid*16)
  const unsigned short* asrc = hbuf + (size_t)((off + m0) >> 7) * (INTERN * 128);

  int brow = tid >> 2;
  int bkg  = tid & 3;
  const float* bsrc = down + (size_t)e * HID * INTERN + (size_t)(n0 + brow) * INTERN + bkg * 8;

  f32x4 acc[4][2];
#pragma unroll
  for (int m = 0; m < 4; ++m)
#pragma unroll
    for (int n = 0; n < 2; ++n) acc[m][n] = (f32x4){0.f, 0.f, 0.f, 0.f};

  char* AsB = (char*)&As[0][0][0];
  int brow_w = brow ^ bkg;

  for (int k0 = 0; k0 < INTERN; k0 += 32) {
    const unsigned short* ak = asrc + (size_t)k0 * 128;   // 4 kgroups * 128 rows * 8
    gload_lds16(ak + (size_t)tid * 8,        AsB + (size_t)tid * 16);
    gload_lds16(ak + 2048 + (size_t)tid * 8, AsB + 4096 + (size_t)tid * 16);
    float4 b0 = *(const float4*)(bsrc + k0);
    float4 b1 = *(const float4*)(bsrc + k0 + 4);
    u16x8 bw;
    bw[0] = f32_to_bf16(b0.x); bw[1] = f32_to_bf16(b0.y);
    bw[2] = f32_to_bf16(b0.z); bw[3] = f32_to_bf16(b0.w);
    bw[4] = f32_to_bf16(b1.x); bw[5] = f32_to_bf16(b1.y);
    bw[6] = f32_to_bf16(b1.z); bw[7] = f32_to_bf16(b1.w);
    *((u16x8*)&Bs[bkg][brow_w][0]) = bw;
    __syncthreads();

    int kg = lane >> 4;
    int rl = lane & 15;
    bf16x8 af[4], bfv[2];
#pragma unroll
    for (int m = 0; m < 4; ++m)
      af[m] = *((const bf16x8*)&As[kg][wm * 64 + m * 16 + rl][0]);
#pragma unroll
    for (int n = 0; n < 2; ++n)
      bfv[n] = *((const bf16x8*)&Bs[kg][(wn * 32 + n * 16 + rl) ^ kg][0]);
#pragma unroll
    for (int m = 0; m < 4; ++m)
#pragma unroll
      for (int n = 0; n < 2; ++n)
        acc[m][n] = __builtin_amdgcn_mfma_f32_16x16x32_bf16(af[m], bfv[n], acc[m][n], 0, 0, 0);
    __syncthreads();
  }

  int rl = lane & 15;
  int rq = lane >> 4;
#pragma unroll
  for (int m = 0; m < 4; ++m) {
#pragma unroll
    for (int n = 0; n < 2; ++n) {
      int col = n0 + wn * 32 + n * 16 + rl;
#pragma unroll
      for (int j = 0; j < 4; ++j) {
        int lr = wm * 64 + m * 16 + rq * 4 + j;
        if (m0 + lr < Ne)
          ybuf[(size_t)(off + m0 + lr) * HID + col] = f32_to_bf16(acc[m][n][j]);
      }
    }
  }
}

// ---------------- final combine: out[t] = sum_k w[t,k] * y[pos[t,k]] ----------------
__global__ void combine_kernel(const int* __restrict__ pos_map,
                               const float* __restrict__ wgt_map,
                               const unsigned short* __restrict__ ybuf,
                               float* __restrict__ out) {
  int i  = blockIdx.x * 256 + threadIdx.x;
  int t  = i >> 7;      // 128 chunks of 8 bf16 per token row
  int c8 = i & 127;
  int p0 = pos_map[2 * t];
  int p1 = pos_map[2 * t + 1];
  float w0 = wgt_map[2 * t];
  float w1 = wgt_map[2 * t + 1];
  float acc[8];
#pragma unroll
  for (int j = 0; j < 8; ++j) acc[j] = 0.f;
  if (p0 >= 0) {
    u16x8 v = *((const u16x8*)(ybuf + (size_t)p0 * HID + c8 * 8));
#pragma unroll
    for (int j = 0; j < 8; ++j) acc[j] += w0 * bf16_to_f32(v[j]);
  }
  if (p1 >= 0) {
    u16x8 v = *((const u16x8*)(ybuf + (size_t)p1 * HID + c8 * 8));
#pragma unroll
    for (int j = 0; j < 8; ++j) acc[j] += w1 * bf16_to_f32(v[j]);
  }
  float4 o0 = make_float4(acc[0], acc[1], acc[2], acc[3]);
  float4 o1 = make_float4(acc[4], acc[5], acc[6], acc[7]);
  float4* dst = (float4*)(out + (size_t)t * HID + c8 * 8);
  dst[0] = o0;
  dst[1] = o1;
}

// ---------------- launch ----------------
extern "C" void kernel_launch(void* const* d_in, const int* in_sizes, int n_in,
                              void* d_out, int out_size, void* d_ws, size_t ws_size,
                              hipStream_t stream) {
  (void)in_sizes; (void)n_in; (void)out_size;
  const float* hidden = (const float*)d_in[0];
  const int*   tki    = (const int*)d_in[1];   // int32 per harness contract
  const float* tkw    = (const float*)d_in[2];
  const float* gup    = (const float*)d_in[3];
  const float* down   = (const float*)d_in[4];
  float* out = (float*)d_out;
  char*  ws  = (char*)d_ws;

  // ws layout (bytes)
  int*   counts   = (int*)  (ws + 0);         // 8 ints
  int*   offsets  = (int*)  (ws + 64);        // 8 ints (128-aligned bases)
  int*   tok_list = (int*)  (ws + 256);       // 8*2048 ints  -> end 65792
  int*   pos_map  = (int*)  (ws + 65792);     // 4096 ints    -> end 82176
  float* wgt_map  = (float*)(ws + 82176);     // 4096 f32     -> end 98560
  float* w_list   = (float*)(ws + 98560);     // 8*2048 f32   -> end 164096
  unsigned short* xb   = (unsigned short*)(ws + 164096);   // 2048*1024 bf16 -> end 4358400
  unsigned short* hbuf = (unsigned short*)(ws + 4358400);  // MAXPOS*2048 bf16 (blocked) -> end 25854208
  unsigned short* ybuf = (unsigned short*)(ws + 25854208); // MAXPOS*1024 bf16 -> end 36602112

  if (ws_size < 36602112ull) return;

  hipLaunchKernelGGL(route_kernel, dim3(1), dim3(256), 0, stream,
                     tki, tkw, counts, offsets, tok_list, w_list, pos_map, wgt_map);
  hipLaunchKernelGGL(cvt_x_kernel, dim3((T_TOK * HID / 4) / 256), dim3(256), 0, stream,
                     hidden, xb);
  hipLaunchKernelGGL(gemm1_kernel, dim3(INTERN / 64, T_TOK / 128, NEXP), dim3(256), 0, stream,
                     xb, gup, counts, offsets, tok_list, hbuf);
  hipLaunchKernelGGL(gemm2_kernel, dim3(HID / 64, T_TOK / 128, NEXP), dim3(256), 0, stream,
                     hbuf, down, counts, offsets, ybuf);
  hipLaunchKernelGGL(combine_kernel, dim3(T_TOK * HID / 8 / 256), dim3(256), 0, stream,
                     pos_map, wgt_map, ybuf, out);
}

// Round 4
// 186.605 us; speedup vs baseline: 1.5344x; 1.0378x over previous
//
#include <hip/hip_runtime.h>
#include <stdint.h>

#define T_TOK  2048
#define HID    1024
#define INTERN 2048
#define NEXP   8
#define MAXPOS 5248   // max 128-aligned routed rows: 4096 + 8*127 -> pad to 5248

typedef __attribute__((ext_vector_type(8))) short          bf16x8;
typedef __attribute__((ext_vector_type(4))) float          f32x4;
typedef __attribute__((ext_vector_type(8))) unsigned short u16x8;
typedef __attribute__((ext_vector_type(4))) unsigned short u16x4;

__device__ __forceinline__ unsigned short f32_to_bf16(float f) {
  unsigned int u = __float_as_uint(f);
  unsigned int r = (u + 0x7FFFu + ((u >> 16) & 1u)) >> 16;
  return (unsigned short)r;
}

__device__ __forceinline__ float bf16_to_f32(unsigned short h) {
  unsigned int u = ((unsigned int)h) << 16;
  return __uint_as_float(u);
}

__device__ __forceinline__ void gload_lds16(const void* g, void* l) {
  __builtin_amdgcn_global_load_lds(
      (const __attribute__((address_space(1))) unsigned int*)g,
      (__attribute__((address_space(3))) unsigned int*)l, 16, 0, 0);
}

// ---------------- routing: build per-expert compact lists (128-aligned offsets) ----------------
__global__ void route_kernel(const int* __restrict__ tki,   // int32 per harness contract
                             const float* __restrict__ tkw,
                             int* __restrict__ counts,
                             int* __restrict__ offsets,     // 128-aligned base per expert
                             int* __restrict__ tok_list,
                             float* __restrict__ w_list,
                             int* __restrict__ pos_map,     // aligned global positions
                             float* __restrict__ wgt_map) {
  __shared__ int scnt[NEXP];
  __shared__ int soff[NEXP];
  int tid = threadIdx.x;
  if (tid < NEXP) scnt[tid] = 0;
  __syncthreads();
  for (int t = tid; t < T_TOK; t += 256) {
    int e0 = tki[2 * t] & 7;
    int e1 = tki[2 * t + 1] & 7;
    float w0 = tkw[2 * t];
    float w1 = tkw[2 * t + 1];
    if (e0 == e1) {
      int p = atomicAdd(&scnt[e0], 1);
      tok_list[e0 * T_TOK + p] = t;
      w_list [e0 * T_TOK + p] = w0 + w1;
      pos_map[2 * t]     = (p << 3) | e0;
      wgt_map[2 * t]     = w0 + w1;
      pos_map[2 * t + 1] = -1;
      wgt_map[2 * t + 1] = 0.0f;
    } else {
      int p = atomicAdd(&scnt[e0], 1);
      tok_list[e0 * T_TOK + p] = t;
      w_list [e0 * T_TOK + p] = w0;
      pos_map[2 * t]     = (p << 3) | e0;
      wgt_map[2 * t]     = w0;
      int q = atomicAdd(&scnt[e1], 1);
      tok_list[e1 * T_TOK + q] = t;
      w_list [e1 * T_TOK + q] = w1;
      pos_map[2 * t + 1] = (q << 3) | e1;
      wgt_map[2 * t + 1] = w1;
    }
  }
  __syncthreads();
  if (tid == 0) {
    int acc = 0;
    for (int e = 0; e < NEXP; ++e) {
      counts[e]  = scnt[e];
      offsets[e] = acc;
      soff[e]    = acc;
      acc += ((scnt[e] + 127) >> 7) << 7;   // 128-aligned segments
    }
  }
  __syncthreads();
  for (int i = tid; i < 2 * T_TOK; i += 256) {
    int v = pos_map[i];
    if (v >= 0) pos_map[i] = soff[v & 7] + (v >> 3);
  }
}

// ---------------- hidden_states f32 -> bf16 (row-major, 4MB; L2-resident) ----------------
__global__ void cvt_x_kernel(const float* __restrict__ x, unsigned short* __restrict__ xb) {
  int i = blockIdx.x * 256 + threadIdx.x;
  float4 v = ((const float4*)x)[i];
  u16x4 o;
  o[0] = f32_to_bf16(v.x); o[1] = f32_to_bf16(v.y);
  o[2] = f32_to_bf16(v.z); o[3] = f32_to_bf16(v.w);
  *((u16x4*)(xb + 4 * (size_t)i)) = o;
}

// ---------------- GEMM1: h = gelu_tanh(X Wg^T) * (X Wu^T), double-buffered ----------------
// Output h in BLOCKED layout: hbuf[(p>>7)*(INTERN*128) + (col>>3)*1024 + (p&127)*8 + (col&7)]
__global__ __launch_bounds__(256, 2)
void gemm1_kernel(const unsigned short* __restrict__ xb,
                  const float* __restrict__ gup,
                  const int* __restrict__ counts,
                  const int* __restrict__ offsets,
                  const int* __restrict__ tok_list,
                  unsigned short* __restrict__ hbuf) {
  int e  = blockIdx.z;
  int Ne = counts[e];
  int m0 = blockIdx.y * 128;
  if (m0 >= Ne) return;
  int n0  = blockIdx.x * 64;
  int off = offsets[e];   // 128-aligned

  __shared__ __align__(16) unsigned short As[2][4][128][8];  // 16 KB
  __shared__ __align__(16) unsigned short Gs[2][4][64][8];   // 8 KB
  __shared__ __align__(16) unsigned short Us[2][4][64][8];   // 8 KB

  int tid  = threadIdx.x;
  int lane = tid & 63;
  int wave = tid >> 6;
  int wm = wave >> 1;
  int wn = wave & 1;

  // A staging: one row per thread, two kg-slots
  int arow = tid & 127;
  int akg  = tid >> 7;
  int rg   = m0 + arow;
  int tok  = (rg < Ne) ? tok_list[e * T_TOK + rg] : 0;
  const unsigned short* asrc = xb + (size_t)tok * HID;

  // B staging: row = tid>>2 (0..63), kg = tid&3 -> 8 consecutive f32
  int brow = tid >> 2;
  int bkg  = tid & 3;
  const float* gsrc = gup + (size_t)e * (2 * INTERN) * HID + (size_t)(n0 + brow) * HID + bkg * 8;
  const float* usrc = gsrc + (size_t)INTERN * HID;
  int brow_w = brow ^ bkg;   // XOR-swizzle rows on write

  f32x4 accg[4][2], accu[4][2];
#pragma unroll
  for (int m = 0; m < 4; ++m)
#pragma unroll
    for (int n = 0; n < 2; ++n) {
      accg[m][n] = (f32x4){0.f, 0.f, 0.f, 0.f};
      accu[m][n] = (f32x4){0.f, 0.f, 0.f, 0.f};
    }

  // ---- prologue: stage tile k0=0 into buffer 0 ----
  {
    char* AsB = (char*)&As[0][0][0][0];
    gload_lds16(asrc + 0 + akg * 8,       AsB + (size_t)tid * 16);
    gload_lds16(asrc + 0 + (akg + 2) * 8, AsB + 4096 + (size_t)tid * 16);
    float4 g0 = *(const float4*)(gsrc + 0);
    float4 g1 = *(const float4*)(gsrc + 4);
    float4 u0 = *(const float4*)(usrc + 0);
    float4 u1 = *(const float4*)(usrc + 4);
    u16x8 gw, uw;
    gw[0] = f32_to_bf16(g0.x); gw[1] = f32_to_bf16(g0.y);
    gw[2] = f32_to_bf16(g0.z); gw[3] = f32_to_bf16(g0.w);
    gw[4] = f32_to_bf16(g1.x); gw[5] = f32_to_bf16(g1.y);
    gw[6] = f32_to_bf16(g1.z); gw[7] = f32_to_bf16(g1.w);
    uw[0] = f32_to_bf16(u0.x); uw[1] = f32_to_bf16(u0.y);
    uw[2] = f32_to_bf16(u0.z); uw[3] = f32_to_bf16(u0.w);
    uw[4] = f32_to_bf16(u1.x); uw[5] = f32_to_bf16(u1.y);
    uw[6] = f32_to_bf16(u1.z); uw[7] = f32_to_bf16(u1.w);
    *((u16x8*)&Gs[0][bkg][brow_w][0]) = gw;
    *((u16x8*)&Us[0][bkg][brow_w][0]) = uw;
  }
  __syncthreads();

  int cur = 0;
  for (int k0 = 0; k0 < HID; k0 += 32) {
    int nxt = cur ^ 1;
    bool pf = (k0 + 32) < HID;
    float4 g0, g1, u0, u1;
    if (pf) {
      int kn = k0 + 32;
      char* AsB = (char*)&As[nxt][0][0][0];
      gload_lds16(asrc + kn + akg * 8,       AsB + (size_t)tid * 16);
      gload_lds16(asrc + kn + (akg + 2) * 8, AsB + 4096 + (size_t)tid * 16);
      g0 = *(const float4*)(gsrc + kn);
      g1 = *(const float4*)(gsrc + kn + 4);
      u0 = *(const float4*)(usrc + kn);
      u1 = *(const float4*)(usrc + kn + 4);
    }

    // compute current tile
    {
      int kg = lane >> 4;
      int rl = lane & 15;
      bf16x8 af[4], gf[2], uf[2];
#pragma unroll
      for (int m = 0; m < 4; ++m)
        af[m] = *((const bf16x8*)&As[cur][kg][wm * 64 + m * 16 + rl][0]);
#pragma unroll
      for (int n = 0; n < 2; ++n) {
        gf[n] = *((const bf16x8*)&Gs[cur][kg][(wn * 32 + n * 16 + rl) ^ kg][0]);
        uf[n] = *((const bf16x8*)&Us[cur][kg][(wn * 32 + n * 16 + rl) ^ kg][0]);
      }
#pragma unroll
      for (int m = 0; m < 4; ++m)
#pragma unroll
        for (int n = 0; n < 2; ++n) {
          accg[m][n] = __builtin_amdgcn_mfma_f32_16x16x32_bf16(af[m], gf[n], accg[m][n], 0, 0, 0);
          accu[m][n] = __builtin_amdgcn_mfma_f32_16x16x32_bf16(af[m], uf[n], accu[m][n], 0, 0, 0);
        }
    }

    if (pf) {
      u16x8 gw, uw;
      gw[0] = f32_to_bf16(g0.x); gw[1] = f32_to_bf16(g0.y);
      gw[2] = f32_to_bf16(g0.z); gw[3] = f32_to_bf16(g0.w);
      gw[4] = f32_to_bf16(g1.x); gw[5] = f32_to_bf16(g1.y);
      gw[6] = f32_to_bf16(g1.z); gw[7] = f32_to_bf16(g1.w);
      uw[0] = f32_to_bf16(u0.x); uw[1] = f32_to_bf16(u0.y);
      uw[2] = f32_to_bf16(u0.z); uw[3] = f32_to_bf16(u0.w);
      uw[4] = f32_to_bf16(u1.x); uw[5] = f32_to_bf16(u1.y);
      uw[6] = f32_to_bf16(u1.z); uw[7] = f32_to_bf16(u1.w);
      *((u16x8*)&Gs[nxt][bkg][brow_w][0]) = gw;
      *((u16x8*)&Us[nxt][bkg][brow_w][0]) = uw;
    }
    __syncthreads();
    cur = nxt;
  }

  int rl = lane & 15;
  int rq = lane >> 4;
  size_t hb_base = (size_t)((off + m0) >> 7) * (INTERN * 128);
#pragma unroll
  for (int m = 0; m < 4; ++m) {
#pragma unroll
    for (int n = 0; n < 2; ++n) {
      int col = n0 + wn * 32 + n * 16 + rl;
      size_t cbase = hb_base + (size_t)(col >> 3) * 1024 + (col & 7);
#pragma unroll
      for (int j = 0; j < 4; ++j) {
        int lr = wm * 64 + m * 16 + rq * 4 + j;   // local row 0..127
        if (m0 + lr < Ne) {
          float gv = accg[m][n][j];
          float uv = accu[m][n][j];
          float t  = gv + 0.044715f * gv * gv * gv;
          float a  = gv / (1.0f + __expf(-1.5957691216f * t));  // == gelu_pytorch_tanh
          hbuf[cbase + (size_t)lr * 8] = f32_to_bf16(a * uv);
        }
      }
    }
  }
}

// ---------------- GEMM2: y = h Wd^T (blocked-A, linear DMA, double-buffered) ----------------
__global__ __launch_bounds__(256, 2)
void gemm2_kernel(const unsigned short* __restrict__ hbuf,
                  const float* __restrict__ down,
                  const int* __restrict__ counts,
                  const int* __restrict__ offsets,
                  unsigned short* __restrict__ ybuf) {
  int e  = blockIdx.z;
  int Ne = counts[e];
  int m0 = blockIdx.y * 128;
  if (m0 >= Ne) return;
  int n0  = blockIdx.x * 64;
  int off = offsets[e];   // 128-aligned

  __shared__ __align__(16) unsigned short As[2][4][128][8];  // 16 KB
  __shared__ __align__(16) unsigned short Bs[2][4][64][8];   // 8 KB

  int tid  = threadIdx.x;
  int lane = tid & 63;
  int wave = tid >> 6;
  int wm = wave >> 1;
  int wn = wave & 1;

  const unsigned short* asrc = hbuf + (size_t)((off + m0) >> 7) * (INTERN * 128);

  int brow = tid >> 2;
  int bkg  = tid & 3;
  const float* bsrc = down + (size_t)e * HID * INTERN + (size_t)(n0 + brow) * INTERN + bkg * 8;
  int brow_w = brow ^ bkg;

  f32x4 acc[4][2];
#pragma unroll
  for (int m = 0; m < 4; ++m)
#pragma unroll
    for (int n = 0; n < 2; ++n) acc[m][n] = (f32x4){0.f, 0.f, 0.f, 0.f};

  // ---- prologue: stage tile k0=0 into buffer 0 ----
  {
    char* AsB = (char*)&As[0][0][0][0];
    const unsigned short* ak = asrc;   // k0 = 0
    gload_lds16(ak + (size_t)tid * 8,        AsB + (size_t)tid * 16);
    gload_lds16(ak + 2048 + (size_t)tid * 8, AsB + 4096 + (size_t)tid * 16);
    float4 b0 = *(const float4*)(bsrc + 0);
    float4 b1 = *(const float4*)(bsrc + 4);
    u16x8 bw;
    bw[0] = f32_to_bf16(b0.x); bw[1] = f32_to_bf16(b0.y);
    bw[2] = f32_to_bf16(b0.z); bw[3] = f32_to_bf16(b0.w);
    bw[4] = f32_to_bf16(b1.x); bw[5] = f32_to_bf16(b1.y);
    bw[6] = f32_to_bf16(b1.z); bw[7] = f32_to_bf16(b1.w);
    *((u16x8*)&Bs[0][bkg][brow_w][0]) = bw;
  }
  __syncthreads();

  int cur = 0;
  for (int k0 = 0; k0 < INTERN; k0 += 32) {
    int nxt = cur ^ 1;
    bool pf = (k0 + 32) < INTERN;
    float4 b0, b1;
    if (pf) {
      int kn = k0 + 32;
      char* AsB = (char*)&As[nxt][0][0][0];
      const unsigned short* ak = asrc + (size_t)kn * 128;
      gload_lds16(ak + (size_t)tid * 8,        AsB + (size_t)tid * 16);
      gload_lds16(ak + 2048 + (size_t)tid * 8, AsB + 4096 + (size_t)tid * 16);
      b0 = *(const float4*)(bsrc + kn);
      b1 = *(const float4*)(bsrc + kn + 4);
    }

    // compute current tile
    {
      int kg = lane >> 4;
      int rl = lane & 15;
      bf16x8 af[4], bfv[2];
#pragma unroll
      for (int m = 0; m < 4; ++m)
        af[m] = *((const bf16x8*)&As[cur][kg][wm * 64 + m * 16 + rl][0]);
#pragma unroll
      for (int n = 0; n < 2; ++n)
        bfv[n] = *((const bf16x8*)&Bs[cur][kg][(wn * 32 + n * 16 + rl) ^ kg][0]);
#pragma unroll
      for (int m = 0; m < 4; ++m)
#pragma unroll
        for (int n = 0; n < 2; ++n)
          acc[m][n] = __builtin_amdgcn_mfma_f32_16x16x32_bf16(af[m], bfv[n], acc[m][n], 0, 0, 0);
    }

    if (pf) {
      u16x8 bw;
      bw[0] = f32_to_bf16(b0.x); bw[1] = f32_to_bf16(b0.y);
      bw[2] = f32_to_bf16(b0.z); bw[3] = f32_to_bf16(b0.w);
      bw[4] = f32_to_bf16(b1.x); bw[5] = f32_to_bf16(b1.y);
      bw[6] = f32_to_bf16(b1.z); bw[7] = f32_to_bf16(b1.w);
      *((u16x8*)&Bs[nxt][bkg][brow_w][0]) = bw;
    }
    __syncthreads();
    cur = nxt;
  }

  int rl = lane & 15;
  int rq = lane >> 4;
#pragma unroll
  for (int m = 0; m < 4; ++m) {
#pragma unroll
    for (int n = 0; n < 2; ++n) {
      int col = n0 + wn * 32 + n * 16 + rl;
#pragma unroll
      for (int j = 0; j < 4; ++j) {
        int lr = wm * 64 + m * 16 + rq * 4 + j;
        if (m0 + lr < Ne)
          ybuf[(size_t)(off + m0 + lr) * HID + col] = f32_to_bf16(acc[m][n][j]);
      }
    }
  }
}

// ---------------- final combine: out[t] = sum_k w[t,k] * y[pos[t,k]] ----------------
__global__ void combine_kernel(const int* __restrict__ pos_map,
                               const float* __restrict__ wgt_map,
                               const unsigned short* __restrict__ ybuf,
                               float* __restrict__ out) {
  int i  = blockIdx.x * 256 + threadIdx.x;
  int t  = i >> 7;      // 128 chunks of 8 bf16 per token row
  int c8 = i & 127;
  int p0 = pos_map[2 * t];
  int p1 = pos_map[2 * t + 1];
  float w0 = wgt_map[2 * t];
  float w1 = wgt_map[2 * t + 1];
  float acc[8];
#pragma unroll
  for (int j = 0; j < 8; ++j) acc[j] = 0.f;
  if (p0 >= 0) {
    u16x8 v = *((const u16x8*)(ybuf + (size_t)p0 * HID + c8 * 8));
#pragma unroll
    for (int j = 0; j < 8; ++j) acc[j] += w0 * bf16_to_f32(v[j]);
  }
  if (p1 >= 0) {
    u16x8 v = *((const u16x8*)(ybuf + (size_t)p1 * HID + c8 * 8));
#pragma unroll
    for (int j = 0; j < 8; ++j) acc[j] += w1 * bf16_to_f32(v[j]);
  }
  float4 o0 = make_float4(acc[0], acc[1], acc[2], acc[3]);
  float4 o1 = make_float4(acc[4], acc[5], acc[6], acc[7]);
  float4* dst = (float4*)(out + (size_t)t * HID + c8 * 8);
  dst[0] = o0;
  dst[1] = o1;
}

// ---------------- launch ----------------
extern "C" void kernel_launch(void* const* d_in, const int* in_sizes, int n_in,
                              void* d_out, int out_size, void* d_ws, size_t ws_size,
                              hipStream_t stream) {
  (void)in_sizes; (void)n_in; (void)out_size;
  const float* hidden = (const float*)d_in[0];
  const int*   tki    = (const int*)d_in[1];   // int32 per harness contract
  const float* tkw    = (const float*)d_in[2];
  const float* gup    = (const float*)d_in[3];
  const float* down   = (const float*)d_in[4];
  float* out = (float*)d_out;
  char*  ws  = (char*)d_ws;

  // ws layout (bytes)
  int*   counts   = (int*)  (ws + 0);         // 8 ints
  int*   offsets  = (int*)  (ws + 64);        // 8 ints (128-aligned bases)
  int*   tok_list = (int*)  (ws + 256);       // 8*2048 ints  -> end 65792
  int*   pos_map  = (int*)  (ws + 65792);     // 4096 ints    -> end 82176
  float* wgt_map  = (float*)(ws + 82176);     // 4096 f32     -> end 98560
  float* w_list   = (float*)(ws + 98560);     // 8*2048 f32   -> end 164096
  unsigned short* xb   = (unsigned short*)(ws + 164096);   // 2048*1024 bf16 -> end 4358400
  unsigned short* hbuf = (unsigned short*)(ws + 4358400);  // MAXPOS*2048 bf16 (blocked) -> end 25854208
  unsigned short* ybuf = (unsigned short*)(ws + 25854208); // MAXPOS*1024 bf16 -> end 36602112

  if (ws_size < 36602112ull) return;

  hipLaunchKernelGGL(route_kernel, dim3(1), dim3(256), 0, stream,
                     tki, tkw, counts, offsets, tok_list, w_list, pos_map, wgt_map);
  hipLaunchKernelGGL(cvt_x_kernel, dim3((T_TOK * HID / 4) / 256), dim3(256), 0, stream,
                     hidden, xb);
  hipLaunchKernelGGL(gemm1_kernel, dim3(INTERN / 64, T_TOK / 128, NEXP), dim3(256), 0, stream,
                     xb, gup, counts, offsets, tok_list, hbuf);
  hipLaunchKernelGGL(gemm2_kernel, dim3(HID / 64, T_TOK / 128, NEXP), dim3(256), 0, stream,
                     hbuf, down, counts, offsets, ybuf);
  hipLaunchKernelGGL(combine_kernel, dim3(T_TOK * HID / 8 / 256), dim3(256), 0, stream,
                     pos_map, wgt_map, ybuf, out);
}

// Round 5
// 154.944 us; speedup vs baseline: 1.8479x; 1.2043x over previous
//
#include <hip/hip_runtime.h>
#include <stdint.h>

#define T_TOK  2048
#define HID    1024
#define INTERN 2048
#define NEXP   8
#define MAXPOS 5248   // max 128-aligned routed rows

typedef __attribute__((ext_vector_type(8))) short          bf16x8;
typedef __attribute__((ext_vector_type(4))) float          f32x4;
typedef __attribute__((ext_vector_type(8))) unsigned short u16x8;
typedef __attribute__((ext_vector_type(4))) unsigned short u16x4;

__device__ __forceinline__ unsigned short f32_to_bf16(float f) {
  unsigned int u = __float_as_uint(f);
  unsigned int r = (u + 0x7FFFu + ((u >> 16) & 1u)) >> 16;
  return (unsigned short)r;
}

__device__ __forceinline__ float bf16_to_f32(unsigned short h) {
  unsigned int u = ((unsigned int)h) << 16;
  return __uint_as_float(u);
}

__device__ __forceinline__ void gload_lds16(const void* g, void* l) {
  __builtin_amdgcn_global_load_lds(
      (const __attribute__((address_space(1))) unsigned int*)g,
      (__attribute__((address_space(3))) unsigned int*)l, 16, 0, 0);
}

__device__ __forceinline__ u16x8 cvt8(float4 a, float4 b) {
  u16x8 w;
  w[0] = f32_to_bf16(a.x); w[1] = f32_to_bf16(a.y);
  w[2] = f32_to_bf16(a.z); w[3] = f32_to_bf16(a.w);
  w[4] = f32_to_bf16(b.x); w[5] = f32_to_bf16(b.y);
  w[6] = f32_to_bf16(b.z); w[7] = f32_to_bf16(b.w);
  return w;
}

#define WAIT_VM0()    asm volatile("s_waitcnt vmcnt(0)" ::: "memory")
#define WAIT_LGKM0()  asm volatile("s_waitcnt lgkmcnt(0)" ::: "memory")
#define SCHED_FENCE() __builtin_amdgcn_sched_barrier(0)

// ---------------- routing ----------------
__global__ void route_kernel(const int* __restrict__ tki,
                             const float* __restrict__ tkw,
                             int* __restrict__ counts,
                             int* __restrict__ offsets,
                             int* __restrict__ tok_list,
                             float* __restrict__ w_list,
                             int* __restrict__ pos_map,
                             float* __restrict__ wgt_map) {
  __shared__ int scnt[NEXP];
  __shared__ int soff[NEXP];
  int tid = threadIdx.x;
  if (tid < NEXP) scnt[tid] = 0;
  __syncthreads();
  for (int t = tid; t < T_TOK; t += 256) {
    int e0 = tki[2 * t] & 7;
    int e1 = tki[2 * t + 1] & 7;
    float w0 = tkw[2 * t];
    float w1 = tkw[2 * t + 1];
    if (e0 == e1) {
      int p = atomicAdd(&scnt[e0], 1);
      tok_list[e0 * T_TOK + p] = t;
      w_list [e0 * T_TOK + p] = w0 + w1;
      pos_map[2 * t]     = (p << 3) | e0;
      wgt_map[2 * t]     = w0 + w1;
      pos_map[2 * t + 1] = -1;
      wgt_map[2 * t + 1] = 0.0f;
    } else {
      int p = atomicAdd(&scnt[e0], 1);
      tok_list[e0 * T_TOK + p] = t;
      w_list [e0 * T_TOK + p] = w0;
      pos_map[2 * t]     = (p << 3) | e0;
      wgt_map[2 * t]     = w0;
      int q = atomicAdd(&scnt[e1], 1);
      tok_list[e1 * T_TOK + q] = t;
      w_list [e1 * T_TOK + q] = w1;
      pos_map[2 * t + 1] = (q << 3) | e1;
      wgt_map[2 * t + 1] = w1;
    }
  }
  __syncthreads();
  if (tid == 0) {
    int acc = 0;
    for (int e = 0; e < NEXP; ++e) {
      counts[e]  = scnt[e];
      offsets[e] = acc;
      soff[e]    = acc;
      acc += ((scnt[e] + 127) >> 7) << 7;
    }
  }
  __syncthreads();
  for (int i = tid; i < 2 * T_TOK; i += 256) {
    int v = pos_map[i];
    if (v >= 0) pos_map[i] = soff[v & 7] + (v >> 3);
  }
}

// ---------------- hidden_states f32 -> bf16 ----------------
__global__ void cvt_x_kernel(const float* __restrict__ x, unsigned short* __restrict__ xb) {
  int i = blockIdx.x * 256 + threadIdx.x;
  float4 v = ((const float4*)x)[i];
  u16x4 o;
  o[0] = f32_to_bf16(v.x); o[1] = f32_to_bf16(v.y);
  o[2] = f32_to_bf16(v.z); o[3] = f32_to_bf16(v.w);
  *((u16x4*)(xb + 4 * (size_t)i)) = o;
}

// ---------------- GEMM1: h = gelu_tanh(X Wg^T) * (X Wu^T)  (BK=64, counted-vmcnt pipeline) ----------------
__global__ __launch_bounds__(256, 2)
void gemm1_kernel(const unsigned short* __restrict__ xb,
                  const float* __restrict__ gup,
                  const int* __restrict__ counts,
                  const int* __restrict__ offsets,
                  const int* __restrict__ tok_list,
                  unsigned short* __restrict__ hbuf) {
  int e  = blockIdx.z;
  int Ne = counts[e];
  int m0 = blockIdx.y * 128;
  if (m0 >= Ne) return;
  int n0  = blockIdx.x * 64;
  int off = offsets[e];

  __shared__ __align__(16) unsigned short As[2][8][128][8];  // 32 KB
  __shared__ __align__(16) unsigned short Gs[2][8][64][8];   // 16 KB
  __shared__ __align__(16) unsigned short Us[2][8][64][8];   // 16 KB

  int tid  = threadIdx.x;
  int lane = tid & 63;
  int wave = tid >> 6;
  int wm = wave >> 1;
  int wn = wave & 1;

  int arow = tid & 127;
  int akg  = tid >> 7;          // 0/1
  int rg   = m0 + arow;
  int tok  = (rg < Ne) ? tok_list[e * T_TOK + rg] : 0;
  const unsigned short* asrc = xb + (size_t)tok * HID;

  int brow = tid >> 2;
  int bq   = tid & 3;
  int kgw0 = bq * 2, kgw1 = bq * 2 + 1;
  const float* gsrc = gup + (size_t)e * (2 * INTERN) * HID + (size_t)(n0 + brow) * HID + bq * 16;
  const float* usrc = gsrc + (size_t)INTERN * HID;

  f32x4 accg[4][2], accu[4][2];
#pragma unroll
  for (int m = 0; m < 4; ++m)
#pragma unroll
    for (int n = 0; n < 2; ++n) {
      accg[m][n] = (f32x4){0.f, 0.f, 0.f, 0.f};
      accu[m][n] = (f32x4){0.f, 0.f, 0.f, 0.f};
    }

  float4 g0, g1, g2, g3, u0, u1, u2, u3;

  // ---- prologue: tile 0 ----
  {
    const float4* gp = (const float4*)gsrc;
    const float4* up = (const float4*)usrc;
    g0 = gp[0]; g1 = gp[1]; g2 = gp[2]; g3 = gp[3];
    u0 = up[0]; u1 = up[1]; u2 = up[2]; u3 = up[3];
    char* base = (char*)&As[0][0][0][0];
#pragma unroll
    for (int o = 0; o < 4; ++o) {
      int kg = o * 2 + akg;
      gload_lds16(asrc + kg * 8, base + o * 4096 + (size_t)tid * 16);
    }
    *((u16x8*)&Gs[0][kgw0][brow ^ kgw0][0]) = cvt8(g0, g1);
    *((u16x8*)&Gs[0][kgw1][brow ^ kgw1][0]) = cvt8(g2, g3);
    *((u16x8*)&Us[0][kgw0][brow ^ kgw0][0]) = cvt8(u0, u1);
    *((u16x8*)&Us[0][kgw1][brow ^ kgw1][0]) = cvt8(u2, u3);
    WAIT_LGKM0(); SCHED_FENCE();
  }

  int cur = 0;
  const int NT = HID / 64;   // 16
  for (int t = 0; t < NT; ++t) {
    WAIT_VM0(); SCHED_FENCE();          // A-DMA(t) landed (only DMA outstanding here)
    __builtin_amdgcn_s_barrier(); SCHED_FENCE();
    int nxt = cur ^ 1;
    int kn = (t + 1 < NT) ? (t + 1) * 64 : 0;   // wrapped dummy prefetch on last iter
    // issue next B loads (registers; consumed after MFMA)
    {
      const float4* gp = (const float4*)(gsrc + kn);
      const float4* up = (const float4*)(usrc + kn);
      g0 = gp[0]; g1 = gp[1]; g2 = gp[2]; g3 = gp[3];
      u0 = up[0]; u1 = up[1]; u2 = up[2]; u3 = up[3];
    }
    // issue next A DMA
    {
      char* base = (char*)&As[nxt][0][0][0];
#pragma unroll
      for (int o = 0; o < 4; ++o) {
        int kg = o * 2 + akg;
        gload_lds16(asrc + kn + kg * 8, base + o * 4096 + (size_t)tid * 16);
      }
    }
    SCHED_FENCE();                       // issues stay above compute
    // compute current tile
#pragma unroll
    for (int kk = 0; kk < 2; ++kk) {
      int kg = kk * 4 + (lane >> 4);
      int rl = lane & 15;
      bf16x8 af[4], gf[2], uf[2];
#pragma unroll
      for (int m = 0; m < 4; ++m)
        af[m] = *((const bf16x8*)&As[cur][kg][wm * 64 + m * 16 + rl][0]);
#pragma unroll
      for (int n = 0; n < 2; ++n) {
        int r = (wn * 32 + n * 16 + rl) ^ kg;
        gf[n] = *((const bf16x8*)&Gs[cur][kg][r][0]);
        uf[n] = *((const bf16x8*)&Us[cur][kg][r][0]);
      }
#pragma unroll
      for (int m = 0; m < 4; ++m)
#pragma unroll
        for (int n = 0; n < 2; ++n) {
          accg[m][n] = __builtin_amdgcn_mfma_f32_16x16x32_bf16(af[m], gf[n], accg[m][n], 0, 0, 0);
          accu[m][n] = __builtin_amdgcn_mfma_f32_16x16x32_bf16(af[m], uf[n], accu[m][n], 0, 0, 0);
        }
    }
    // stage next B into LDS (compiler inserts exact vmcnt for register deps)
    *((u16x8*)&Gs[nxt][kgw0][brow ^ kgw0][0]) = cvt8(g0, g1);
    *((u16x8*)&Gs[nxt][kgw1][brow ^ kgw1][0]) = cvt8(g2, g3);
    *((u16x8*)&Us[nxt][kgw0][brow ^ kgw0][0]) = cvt8(u0, u1);
    *((u16x8*)&Us[nxt][kgw1][brow ^ kgw1][0]) = cvt8(u2, u3);
    WAIT_LGKM0(); SCHED_FENCE();         // ds_writes visible before next barrier
    cur = nxt;
  }
  WAIT_VM0();                            // drain dummy prefetch

  int rl = lane & 15;
  int rq = lane >> 4;
  size_t hb_base = (size_t)((off + m0) >> 7) * (INTERN * 128);
#pragma unroll
  for (int m = 0; m < 4; ++m) {
#pragma unroll
    for (int n = 0; n < 2; ++n) {
      int col = n0 + wn * 32 + n * 16 + rl;
      size_t cbase = hb_base + (size_t)(col >> 3) * 1024 + (col & 7);
#pragma unroll
      for (int j = 0; j < 4; ++j) {
        int lr = wm * 64 + m * 16 + rq * 4 + j;
        if (m0 + lr < Ne) {
          float gv = accg[m][n][j];
          float uv = accu[m][n][j];
          float tt = gv + 0.044715f * gv * gv * gv;
          float a  = gv / (1.0f + __expf(-1.5957691216f * tt));  // == gelu_pytorch_tanh
          hbuf[cbase + (size_t)lr * 8] = f32_to_bf16(a * uv);
        }
      }
    }
  }
}

// ---------------- GEMM2: y = h Wd^T  (blocked-A, BK=64, counted-vmcnt pipeline) ----------------
__global__ __launch_bounds__(256, 2)
void gemm2_kernel(const unsigned short* __restrict__ hbuf,
                  const float* __restrict__ down,
                  const int* __restrict__ counts,
                  const int* __restrict__ offsets,
                  unsigned short* __restrict__ ybuf) {
  int e  = blockIdx.z;
  int Ne = counts[e];
  int m0 = blockIdx.y * 128;
  if (m0 >= Ne) return;
  int n0  = blockIdx.x * 64;
  int off = offsets[e];

  __shared__ __align__(16) unsigned short As[2][8][128][8];  // 32 KB
  __shared__ __align__(16) unsigned short Bs[2][8][64][8];   // 16 KB

  int tid  = threadIdx.x;
  int lane = tid & 63;
  int wave = tid >> 6;
  int wm = wave >> 1;
  int wn = wave & 1;

  const unsigned short* asrc = hbuf + (size_t)((off + m0) >> 7) * (INTERN * 128);

  int brow = tid >> 2;
  int bq   = tid & 3;
  int kgw0 = bq * 2, kgw1 = bq * 2 + 1;
  const float* bsrc = down + (size_t)e * HID * INTERN + (size_t)(n0 + brow) * INTERN + bq * 16;

  f32x4 acc[4][2];
#pragma unroll
  for (int m = 0; m < 4; ++m)
#pragma unroll
    for (int n = 0; n < 2; ++n) acc[m][n] = (f32x4){0.f, 0.f, 0.f, 0.f};

  float4 b0, b1, b2, b3;

  // ---- prologue: tile 0 ----
  {
    const float4* bp = (const float4*)bsrc;
    b0 = bp[0]; b1 = bp[1]; b2 = bp[2]; b3 = bp[3];
    char* base = (char*)&As[0][0][0][0];
#pragma unroll
    for (int o = 0; o < 4; ++o)
      gload_lds16(asrc + o * 2048 + (size_t)tid * 8, base + o * 4096 + (size_t)tid * 16);
    *((u16x8*)&Bs[0][kgw0][brow ^ kgw0][0]) = cvt8(b0, b1);
    *((u16x8*)&Bs[0][kgw1][brow ^ kgw1][0]) = cvt8(b2, b3);
    WAIT_LGKM0(); SCHED_FENCE();
  }

  int cur = 0;
  const int NT = INTERN / 64;   // 32
  for (int t = 0; t < NT; ++t) {
    WAIT_VM0(); SCHED_FENCE();
    __builtin_amdgcn_s_barrier(); SCHED_FENCE();
    int nxt = cur ^ 1;
    int kn = (t + 1 < NT) ? (t + 1) * 64 : 0;
    // issue next B loads
    {
      const float4* bp = (const float4*)(bsrc + kn);
      b0 = bp[0]; b1 = bp[1]; b2 = bp[2]; b3 = bp[3];
    }
    // issue next A DMA (fully linear: blocked hbuf layout)
    {
      char* base = (char*)&As[nxt][0][0][0];
      const unsigned short* ak = asrc + (size_t)kn * 128;
#pragma unroll
      for (int o = 0; o < 4; ++o)
        gload_lds16(ak + o * 2048 + (size_t)tid * 8, base + o * 4096 + (size_t)tid * 16);
    }
    SCHED_FENCE();
    // compute current tile
#pragma unroll
    for (int kk = 0; kk < 2; ++kk) {
      int kg = kk * 4 + (lane >> 4);
      int rl = lane & 15;
      bf16x8 af[4], bfv[2];
#pragma unroll
      for (int m = 0; m < 4; ++m)
        af[m] = *((const bf16x8*)&As[cur][kg][wm * 64 + m * 16 + rl][0]);
#pragma unroll
      for (int n = 0; n < 2; ++n)
        bfv[n] = *((const bf16x8*)&Bs[cur][kg][(wn * 32 + n * 16 + rl) ^ kg][0]);
#pragma unroll
      for (int m = 0; m < 4; ++m)
#pragma unroll
        for (int n = 0; n < 2; ++n)
          acc[m][n] = __builtin_amdgcn_mfma_f32_16x16x32_bf16(af[m], bfv[n], acc[m][n], 0, 0, 0);
    }
    // stage next B
    *((u16x8*)&Bs[nxt][kgw0][brow ^ kgw0][0]) = cvt8(b0, b1);
    *((u16x8*)&Bs[nxt][kgw1][brow ^ kgw1][0]) = cvt8(b2, b3);
    WAIT_LGKM0(); SCHED_FENCE();
    cur = nxt;
  }
  WAIT_VM0();

  int rl = lane & 15;
  int rq = lane >> 4;
#pragma unroll
  for (int m = 0; m < 4; ++m) {
#pragma unroll
    for (int n = 0; n < 2; ++n) {
      int col = n0 + wn * 32 + n * 16 + rl;
#pragma unroll
      for (int j = 0; j < 4; ++j) {
        int lr = wm * 64 + m * 16 + rq * 4 + j;
        if (m0 + lr < Ne)
          ybuf[(size_t)(off + m0 + lr) * HID + col] = f32_to_bf16(acc[m][n][j]);
      }
    }
  }
}

// ---------------- final combine ----------------
__global__ void combine_kernel(const int* __restrict__ pos_map,
                               const float* __restrict__ wgt_map,
                               const unsigned short* __restrict__ ybuf,
                               float* __restrict__ out) {
  int i  = blockIdx.x * 256 + threadIdx.x;
  int t  = i >> 7;
  int c8 = i & 127;
  int p0 = pos_map[2 * t];
  int p1 = pos_map[2 * t + 1];
  float w0 = wgt_map[2 * t];
  float w1 = wgt_map[2 * t + 1];
  float acc[8];
#pragma unroll
  for (int j = 0; j < 8; ++j) acc[j] = 0.f;
  if (p0 >= 0) {
    u16x8 v = *((const u16x8*)(ybuf + (size_t)p0 * HID + c8 * 8));
#pragma unroll
    for (int j = 0; j < 8; ++j) acc[j] += w0 * bf16_to_f32(v[j]);
  }
  if (p1 >= 0) {
    u16x8 v = *((const u16x8*)(ybuf + (size_t)p1 * HID + c8 * 8));
#pragma unroll
    for (int j = 0; j < 8; ++j) acc[j] += w1 * bf16_to_f32(v[j]);
  }
  float4 o0 = make_float4(acc[0], acc[1], acc[2], acc[3]);
  float4 o1 = make_float4(acc[4], acc[5], acc[6], acc[7]);
  float4* dst = (float4*)(out + (size_t)t * HID + c8 * 8);
  dst[0] = o0;
  dst[1] = o1;
}

// ---------------- launch ----------------
extern "C" void kernel_launch(void* const* d_in, const int* in_sizes, int n_in,
                              void* d_out, int out_size, void* d_ws, size_t ws_size,
                              hipStream_t stream) {
  (void)in_sizes; (void)n_in; (void)out_size;
  const float* hidden = (const float*)d_in[0];
  const int*   tki    = (const int*)d_in[1];
  const float* tkw    = (const float*)d_in[2];
  const float* gup    = (const float*)d_in[3];
  const float* down   = (const float*)d_in[4];
  float* out = (float*)d_out;
  char*  ws  = (char*)d_ws;

  int*   counts   = (int*)  (ws + 0);
  int*   offsets  = (int*)  (ws + 64);
  int*   tok_list = (int*)  (ws + 256);
  int*   pos_map  = (int*)  (ws + 65792);
  float* wgt_map  = (float*)(ws + 82176);
  float* w_list   = (float*)(ws + 98560);
  unsigned short* xb   = (unsigned short*)(ws + 164096);
  unsigned short* hbuf = (unsigned short*)(ws + 4358400);
  unsigned short* ybuf = (unsigned short*)(ws + 25854208);

  if (ws_size < 36602112ull) return;

  hipLaunchKernelGGL(route_kernel, dim3(1), dim3(256), 0, stream,
                     tki, tkw, counts, offsets, tok_list, w_list, pos_map, wgt_map);
  hipLaunchKernelGGL(cvt_x_kernel, dim3((T_TOK * HID / 4) / 256), dim3(256), 0, stream,
                     hidden, xb);
  hipLaunchKernelGGL(gemm1_kernel, dim3(INTERN / 64, T_TOK / 128, NEXP), dim3(256), 0, stream,
                     xb, gup, counts, offsets, tok_list, hbuf);
  hipLaunchKernelGGL(gemm2_kernel, dim3(HID / 64, T_TOK / 128, NEXP), dim3(256), 0, stream,
                     hbuf, down, counts, offsets, ybuf);
  hipLaunchKernelGGL(combine_kernel, dim3(T_TOK * HID / 8 / 256), dim3(256), 0, stream,
                     pos_map, wgt_map, ybuf, out);
}

// Round 6
// 143.735 us; speedup vs baseline: 1.9920x; 1.0780x over previous
//
#include <hip/hip_runtime.h>
#include <stdint.h>

#define T_TOK  2048
#define HID    1024
#define INTERN 2048
#define NEXP   8
#define MAXPOS 5248   // max 128-aligned routed rows

typedef __attribute__((ext_vector_type(8))) short          bf16x8;
typedef __attribute__((ext_vector_type(4))) float          f32x4;
typedef __attribute__((ext_vector_type(8))) unsigned short u16x8;
typedef __attribute__((ext_vector_type(4))) unsigned short u16x4;

__device__ __forceinline__ unsigned short f32_to_bf16(float f) {
  unsigned int u = __float_as_uint(f);
  unsigned int r = (u + 0x7FFFu + ((u >> 16) & 1u)) >> 16;
  return (unsigned short)r;
}

__device__ __forceinline__ float bf16_to_f32(unsigned short h) {
  unsigned int u = ((unsigned int)h) << 16;
  return __uint_as_float(u);
}

__device__ __forceinline__ void gload_lds16(const void* g, void* l) {
  __builtin_amdgcn_global_load_lds(
      (const __attribute__((address_space(1))) unsigned int*)g,
      (__attribute__((address_space(3))) unsigned int*)l, 16, 0, 0);
}

__device__ __forceinline__ u16x8 cvt8(float4 a, float4 b) {
  u16x8 w;
  w[0] = f32_to_bf16(a.x); w[1] = f32_to_bf16(a.y);
  w[2] = f32_to_bf16(a.z); w[3] = f32_to_bf16(a.w);
  w[4] = f32_to_bf16(b.x); w[5] = f32_to_bf16(b.y);
  w[6] = f32_to_bf16(b.z); w[7] = f32_to_bf16(b.w);
  return w;
}

#define WAIT_VM0()    asm volatile("s_waitcnt vmcnt(0)" ::: "memory")
#define WAIT_LGKM0()  asm volatile("s_waitcnt lgkmcnt(0)" ::: "memory")
#define SCHED_FENCE() __builtin_amdgcn_sched_barrier(0)

// ---------------- routing ----------------
__global__ void route_kernel(const int* __restrict__ tki,
                             const float* __restrict__ tkw,
                             int* __restrict__ counts,
                             int* __restrict__ offsets,
                             int* __restrict__ tok_list,
                             float* __restrict__ w_list,
                             int* __restrict__ pos_map,
                             float* __restrict__ wgt_map) {
  __shared__ int scnt[NEXP];
  __shared__ int soff[NEXP];
  int tid = threadIdx.x;
  if (tid < NEXP) scnt[tid] = 0;
  __syncthreads();
  for (int t = tid; t < T_TOK; t += 256) {
    int e0 = tki[2 * t] & 7;
    int e1 = tki[2 * t + 1] & 7;
    float w0 = tkw[2 * t];
    float w1 = tkw[2 * t + 1];
    if (e0 == e1) {
      int p = atomicAdd(&scnt[e0], 1);
      tok_list[e0 * T_TOK + p] = t;
      w_list [e0 * T_TOK + p] = w0 + w1;
      pos_map[2 * t]     = (p << 3) | e0;
      wgt_map[2 * t]     = w0 + w1;
      pos_map[2 * t + 1] = -1;
      wgt_map[2 * t + 1] = 0.0f;
    } else {
      int p = atomicAdd(&scnt[e0], 1);
      tok_list[e0 * T_TOK + p] = t;
      w_list [e0 * T_TOK + p] = w0;
      pos_map[2 * t]     = (p << 3) | e0;
      wgt_map[2 * t]     = w0;
      int q = atomicAdd(&scnt[e1], 1);
      tok_list[e1 * T_TOK + q] = t;
      w_list [e1 * T_TOK + q] = w1;
      pos_map[2 * t + 1] = (q << 3) | e1;
      wgt_map[2 * t + 1] = w1;
    }
  }
  __syncthreads();
  if (tid == 0) {
    int acc = 0;
    for (int e = 0; e < NEXP; ++e) {
      counts[e]  = scnt[e];
      offsets[e] = acc;
      soff[e]    = acc;
      acc += ((scnt[e] + 127) >> 7) << 7;
    }
  }
  __syncthreads();
  for (int i = tid; i < 2 * T_TOK; i += 256) {
    int v = pos_map[i];
    if (v >= 0) pos_map[i] = soff[v & 7] + (v >> 3);
  }
}

// ---------------- hidden_states f32 -> bf16 ----------------
__global__ void cvt_x_kernel(const float* __restrict__ x, unsigned short* __restrict__ xb) {
  int i = blockIdx.x * 256 + threadIdx.x;
  float4 v = ((const float4*)x)[i];
  u16x4 o;
  o[0] = f32_to_bf16(v.x); o[1] = f32_to_bf16(v.y);
  o[2] = f32_to_bf16(v.z); o[3] = f32_to_bf16(v.w);
  *((u16x4*)(xb + 4 * (size_t)i)) = o;
}

// ---------------- GEMM1: h = gelu_tanh(X Wg^T) * (X Wu^T) ----------------
// BK=32, double-buffered, counted-vmcnt single-barrier pipeline, 32 KB LDS (5 blocks/CU).
__global__ __launch_bounds__(256, 4)
void gemm1_kernel(const unsigned short* __restrict__ xb,
                  const float* __restrict__ gup,
                  const int* __restrict__ counts,
                  const int* __restrict__ offsets,
                  const int* __restrict__ tok_list,
                  unsigned short* __restrict__ hbuf) {
  int e  = blockIdx.z;
  int Ne = counts[e];
  int m0 = blockIdx.y * 128;
  if (m0 >= Ne) return;
  int n0  = blockIdx.x * 64;
  int off = offsets[e];

  __shared__ __align__(16) unsigned short As[2][4][128][8];  // 16 KB
  __shared__ __align__(16) unsigned short Gs[2][4][64][8];   // 8 KB
  __shared__ __align__(16) unsigned short Us[2][4][64][8];   // 8 KB

  int tid  = threadIdx.x;
  int lane = tid & 63;
  int wave = tid >> 6;
  int wm = wave >> 1;
  int wn = wave & 1;

  int arow = tid & 127;
  int akg  = tid >> 7;          // 0/1
  int rg   = m0 + arow;
  int tok  = (rg < Ne) ? tok_list[e * T_TOK + rg] : 0;
  const unsigned short* asrc = xb + (size_t)tok * HID;

  int brow = tid >> 2;
  int bq   = tid & 3;           // k-group 0..3
  const float* gsrc = gup + (size_t)e * (2 * INTERN) * HID + (size_t)(n0 + brow) * HID + bq * 8;
  const float* usrc = gsrc + (size_t)INTERN * HID;
  int brw = brow ^ bq;          // XOR-swizzled write row

  f32x4 accg[4][2], accu[4][2];
#pragma unroll
  for (int m = 0; m < 4; ++m)
#pragma unroll
    for (int n = 0; n < 2; ++n) {
      accg[m][n] = (f32x4){0.f, 0.f, 0.f, 0.f};
      accu[m][n] = (f32x4){0.f, 0.f, 0.f, 0.f};
    }

  float4 g0, g1, u0, u1;

  // ---- prologue: tile 0 ----
  {
    const float4* gp = (const float4*)gsrc;
    const float4* up = (const float4*)usrc;
    g0 = gp[0]; g1 = gp[1];
    u0 = up[0]; u1 = up[1];
    char* base = (char*)&As[0][0][0][0];
    gload_lds16(asrc + akg * 8,       base + (size_t)tid * 16);
    gload_lds16(asrc + (akg + 2) * 8, base + 4096 + (size_t)tid * 16);
    *((u16x8*)&Gs[0][bq][brw][0]) = cvt8(g0, g1);
    *((u16x8*)&Us[0][bq][brw][0]) = cvt8(u0, u1);
    WAIT_LGKM0(); SCHED_FENCE();
  }

  int cur = 0;
  const int NT = HID / 32;   // 32
  for (int t = 0; t < NT; ++t) {
    WAIT_VM0(); SCHED_FENCE();          // A-DMA(t) landed (only DMA outstanding here)
    __builtin_amdgcn_s_barrier(); SCHED_FENCE();
    int nxt = cur ^ 1;
    int kn = (t + 1 < NT) ? (t + 1) * 32 : 0;   // wrapped dummy prefetch on last iter
    // issue next B loads (registers; consumed after MFMA)
    {
      const float4* gp = (const float4*)(gsrc + kn);
      const float4* up = (const float4*)(usrc + kn);
      g0 = gp[0]; g1 = gp[1];
      u0 = up[0]; u1 = up[1];
    }
    // issue next A DMA
    {
      char* base = (char*)&As[nxt][0][0][0];
      gload_lds16(asrc + kn + akg * 8,       base + (size_t)tid * 16);
      gload_lds16(asrc + kn + (akg + 2) * 8, base + 4096 + (size_t)tid * 16);
    }
    SCHED_FENCE();                       // issues stay above compute
    // compute current tile (16 MFMA)
    {
      int kg = lane >> 4;
      int rl = lane & 15;
      bf16x8 af[4], gf[2], uf[2];
#pragma unroll
      for (int m = 0; m < 4; ++m)
        af[m] = *((const bf16x8*)&As[cur][kg][wm * 64 + m * 16 + rl][0]);
#pragma unroll
      for (int n = 0; n < 2; ++n) {
        int r = (wn * 32 + n * 16 + rl) ^ kg;
        gf[n] = *((const bf16x8*)&Gs[cur][kg][r][0]);
        uf[n] = *((const bf16x8*)&Us[cur][kg][r][0]);
      }
#pragma unroll
      for (int m = 0; m < 4; ++m)
#pragma unroll
        for (int n = 0; n < 2; ++n) {
          accg[m][n] = __builtin_amdgcn_mfma_f32_16x16x32_bf16(af[m], gf[n], accg[m][n], 0, 0, 0);
          accu[m][n] = __builtin_amdgcn_mfma_f32_16x16x32_bf16(af[m], uf[n], accu[m][n], 0, 0, 0);
        }
    }
    // stage next B into LDS (compiler inserts exact vmcnt for register deps)
    *((u16x8*)&Gs[nxt][bq][brw][0]) = cvt8(g0, g1);
    *((u16x8*)&Us[nxt][bq][brw][0]) = cvt8(u0, u1);
    WAIT_LGKM0(); SCHED_FENCE();         // ds_writes visible before next barrier
    cur = nxt;
  }
  WAIT_VM0();                            // drain dummy prefetch

  int rl = lane & 15;
  int rq = lane >> 4;
  size_t hb_base = (size_t)((off + m0) >> 7) * (INTERN * 128);
#pragma unroll
  for (int m = 0; m < 4; ++m) {
#pragma unroll
    for (int n = 0; n < 2; ++n) {
      int col = n0 + wn * 32 + n * 16 + rl;
      size_t cbase = hb_base + (size_t)(col >> 3) * 1024 + (col & 7);
#pragma unroll
      for (int j = 0; j < 4; ++j) {
        int lr = wm * 64 + m * 16 + rq * 4 + j;
        if (m0 + lr < Ne) {
          float gv = accg[m][n][j];
          float uv = accu[m][n][j];
          float tt = gv + 0.044715f * gv * gv * gv;
          float a  = gv / (1.0f + __expf(-1.5957691216f * tt));  // == gelu_pytorch_tanh
          hbuf[cbase + (size_t)lr * 8] = f32_to_bf16(a * uv);
        }
      }
    }
  }
}

// ---------------- GEMM2: y = h Wd^T  (blocked-A, BK=64, counted-vmcnt pipeline) ----------------
__global__ __launch_bounds__(256, 2)
void gemm2_kernel(const unsigned short* __restrict__ hbuf,
                  const float* __restrict__ down,
                  const int* __restrict__ counts,
                  const int* __restrict__ offsets,
                  unsigned short* __restrict__ ybuf) {
  int e  = blockIdx.z;
  int Ne = counts[e];
  int m0 = blockIdx.y * 128;
  if (m0 >= Ne) return;
  int n0  = blockIdx.x * 64;
  int off = offsets[e];

  __shared__ __align__(16) unsigned short As[2][8][128][8];  // 32 KB
  __shared__ __align__(16) unsigned short Bs[2][8][64][8];   // 16 KB

  int tid  = threadIdx.x;
  int lane = tid & 63;
  int wave = tid >> 6;
  int wm = wave >> 1;
  int wn = wave & 1;

  const unsigned short* asrc = hbuf + (size_t)((off + m0) >> 7) * (INTERN * 128);

  int brow = tid >> 2;
  int bq   = tid & 3;
  int kgw0 = bq * 2, kgw1 = bq * 2 + 1;
  const float* bsrc = down + (size_t)e * HID * INTERN + (size_t)(n0 + brow) * INTERN + bq * 16;

  f32x4 acc[4][2];
#pragma unroll
  for (int m = 0; m < 4; ++m)
#pragma unroll
    for (int n = 0; n < 2; ++n) acc[m][n] = (f32x4){0.f, 0.f, 0.f, 0.f};

  float4 b0, b1, b2, b3;

  // ---- prologue: tile 0 ----
  {
    const float4* bp = (const float4*)bsrc;
    b0 = bp[0]; b1 = bp[1]; b2 = bp[2]; b3 = bp[3];
    char* base = (char*)&As[0][0][0][0];
#pragma unroll
    for (int o = 0; o < 4; ++o)
      gload_lds16(asrc + o * 2048 + (size_t)tid * 8, base + o * 4096 + (size_t)tid * 16);
    *((u16x8*)&Bs[0][kgw0][brow ^ kgw0][0]) = cvt8(b0, b1);
    *((u16x8*)&Bs[0][kgw1][brow ^ kgw1][0]) = cvt8(b2, b3);
    WAIT_LGKM0(); SCHED_FENCE();
  }

  int cur = 0;
  const int NT = INTERN / 64;   // 32
  for (int t = 0; t < NT; ++t) {
    WAIT_VM0(); SCHED_FENCE();
    __builtin_amdgcn_s_barrier(); SCHED_FENCE();
    int nxt = cur ^ 1;
    int kn = (t + 1 < NT) ? (t + 1) * 64 : 0;
    // issue next B loads
    {
      const float4* bp = (const float4*)(bsrc + kn);
      b0 = bp[0]; b1 = bp[1]; b2 = bp[2]; b3 = bp[3];
    }
    // issue next A DMA (fully linear: blocked hbuf layout)
    {
      char* base = (char*)&As[nxt][0][0][0];
      const unsigned short* ak = asrc + (size_t)kn * 128;
#pragma unroll
      for (int o = 0; o < 4; ++o)
        gload_lds16(ak + o * 2048 + (size_t)tid * 8, base + o * 4096 + (size_t)tid * 16);
    }
    SCHED_FENCE();
    // compute current tile
#pragma unroll
    for (int kk = 0; kk < 2; ++kk) {
      int kg = kk * 4 + (lane >> 4);
      int rl = lane & 15;
      bf16x8 af[4], bfv[2];
#pragma unroll
      for (int m = 0; m < 4; ++m)
        af[m] = *((const bf16x8*)&As[cur][kg][wm * 64 + m * 16 + rl][0]);
#pragma unroll
      for (int n = 0; n < 2; ++n)
        bfv[n] = *((const bf16x8*)&Bs[cur][kg][(wn * 32 + n * 16 + rl) ^ kg][0]);
#pragma unroll
      for (int m = 0; m < 4; ++m)
#pragma unroll
        for (int n = 0; n < 2; ++n)
          acc[m][n] = __builtin_amdgcn_mfma_f32_16x16x32_bf16(af[m], bfv[n], acc[m][n], 0, 0, 0);
    }
    // stage next B
    *((u16x8*)&Bs[nxt][kgw0][brow ^ kgw0][0]) = cvt8(b0, b1);
    *((u16x8*)&Bs[nxt][kgw1][brow ^ kgw1][0]) = cvt8(b2, b3);
    WAIT_LGKM0(); SCHED_FENCE();
    cur = nxt;
  }
  WAIT_VM0();

  int rl = lane & 15;
  int rq = lane >> 4;
#pragma unroll
  for (int m = 0; m < 4; ++m) {
#pragma unroll
    for (int n = 0; n < 2; ++n) {
      int col = n0 + wn * 32 + n * 16 + rl;
#pragma unroll
      for (int j = 0; j < 4; ++j) {
        int lr = wm * 64 + m * 16 + rq * 4 + j;
        if (m0 + lr < Ne)
          ybuf[(size_t)(off + m0 + lr) * HID + col] = f32_to_bf16(acc[m][n][j]);
      }
    }
  }
}

// ---------------- final combine ----------------
__global__ void combine_kernel(const int* __restrict__ pos_map,
                               const float* __restrict__ wgt_map,
                               const unsigned short* __restrict__ ybuf,
                               float* __restrict__ out) {
  int i  = blockIdx.x * 256 + threadIdx.x;
  int t  = i >> 7;
  int c8 = i & 127;
  int p0 = pos_map[2 * t];
  int p1 = pos_map[2 * t + 1];
  float w0 = wgt_map[2 * t];
  float w1 = wgt_map[2 * t + 1];
  float acc[8];
#pragma unroll
  for (int j = 0; j < 8; ++j) acc[j] = 0.f;
  if (p0 >= 0) {
    u16x8 v = *((const u16x8*)(ybuf + (size_t)p0 * HID + c8 * 8));
#pragma unroll
    for (int j = 0; j < 8; ++j) acc[j] += w0 * bf16_to_f32(v[j]);
  }
  if (p1 >= 0) {
    u16x8 v = *((const u16x8*)(ybuf + (size_t)p1 * HID + c8 * 8));
#pragma unroll
    for (int j = 0; j < 8; ++j) acc[j] += w1 * bf16_to_f32(v[j]);
  }
  float4 o0 = make_float4(acc[0], acc[1], acc[2], acc[3]);
  float4 o1 = make_float4(acc[4], acc[5], acc[6], acc[7]);
  float4* dst = (float4*)(out + (size_t)t * HID + c8 * 8);
  dst[0] = o0;
  dst[1] = o1;
}

// ---------------- launch ----------------
extern "C" void kernel_launch(void* const* d_in, const int* in_sizes, int n_in,
                              void* d_out, int out_size, void* d_ws, size_t ws_size,
                              hipStream_t stream) {
  (void)in_sizes; (void)n_in; (void)out_size;
  const float* hidden = (const float*)d_in[0];
  const int*   tki    = (const int*)d_in[1];
  const float* tkw    = (const float*)d_in[2];
  const float* gup    = (const float*)d_in[3];
  const float* down   = (const float*)d_in[4];
  float* out = (float*)d_out;
  char*  ws  = (char*)d_ws;

  int*   counts   = (int*)  (ws + 0);
  int*   offsets  = (int*)  (ws + 64);
  int*   tok_list = (int*)  (ws + 256);
  int*   pos_map  = (int*)  (ws + 65792);
  float* wgt_map  = (float*)(ws + 82176);
  float* w_list   = (float*)(ws + 98560);
  unsigned short* xb   = (unsigned short*)(ws + 164096);
  unsigned short* hbuf = (unsigned short*)(ws + 4358400);
  unsigned short* ybuf = (unsigned short*)(ws + 25854208);

  if (ws_size < 36602112ull) return;

  hipLaunchKernelGGL(route_kernel, dim3(1), dim3(256), 0, stream,
                     tki, tkw, counts, offsets, tok_list, w_list, pos_map, wgt_map);
  hipLaunchKernelGGL(cvt_x_kernel, dim3((T_TOK * HID / 4) / 256), dim3(256), 0, stream,
                     hidden, xb);
  hipLaunchKernelGGL(gemm1_kernel, dim3(INTERN / 64, T_TOK / 128, NEXP), dim3(256), 0, stream,
                     xb, gup, counts, offsets, tok_list, hbuf);
  hipLaunchKernelGGL(gemm2_kernel, dim3(HID / 64, T_TOK / 128, NEXP), dim3(256), 0, stream,
                     hbuf, down, counts, offsets, ybuf);
  hipLaunchKernelGGL(combine_kernel, dim3(T_TOK * HID / 8 / 256), dim3(256), 0, stream,
                     pos_map, wgt_map, ybuf, out);
}